// Round 1
// baseline (317.516 us; speedup 1.0000x reference)
//
#include <hip/hip_runtime.h>
#include <stdint.h>
#include <stddef.h>

// Problem constants
#define NB   16
#define NC   64
#define NH   64
#define NW   64
#define KC   16
#define NOUT 64
#define NRANK 8
#define NMLP 32
#define NF   576      // C*3*3
#define NPIX 4096     // H*W

typedef short s16x8 __attribute__((ext_vector_type(8)));
typedef float f32x4 __attribute__((ext_vector_type(4)));

__device__ __forceinline__ unsigned short f2bf(float x) {
    union { float f; uint32_t u; } v; v.f = x;
    uint32_t r = v.u + 0x7FFFu + ((v.u >> 16) & 1u);   // RTNE
    return (unsigned short)(r >> 16);
}

// ---------------------------------------------------------------------------
// Kernel 1: per-(b,k) pixel lists (order-preserving compaction) + counts +
// cluster centers (segmented mean of 576-dim patches).
// grid 256 = (k*16 + b)  [b fastest => all k of a batch on one XCD]
// ---------------------------------------------------------------------------
extern "C" __global__ __launch_bounds__(576)
void k_centers(const float* __restrict__ x, const int* __restrict__ labels,
               unsigned short* __restrict__ lists, int* __restrict__ counts,
               float* __restrict__ centers)
{
    const int bk = blockIdx.x;
    const int b = bk & 15, k = bk >> 4;
    __shared__ unsigned short list[NPIX];   // 8 KB
    __shared__ int wcnt[9];
    const int tid = threadIdx.x;
    const int lane = tid & 63, wv = tid >> 6;
    const int* lab = labels + b * NPIX;

    int total = 0;
    for (int base = 0; base < NPIX; base += 576) {
        int n = base + tid;
        bool pred = (n < NPIX) && (lab[n] == k);
        unsigned long long m = __ballot(pred);
        if (lane == 0) wcnt[wv] = __popcll(m);
        int pre = __popcll(m & ((1ull << lane) - 1ull));
        __syncthreads();
        int wbase = total;
        for (int i = 0; i < wv; ++i) wbase += wcnt[i];
        int nt = total;
        for (int i = 0; i < 9; ++i) nt += wcnt[i];
        if (pred) list[wbase + pre] = (unsigned short)n;
        total = nt;
        __syncthreads();
    }
    const int cnt = total;
    unsigned short* gl = lists + bk * NPIX;
    for (int i = tid; i < cnt; i += 576) gl[i] = list[i];
    if (tid == 0) counts[bk] = cnt;

    // one thread per feature f = c*9 + dy*3 + dx  (torch Unfold order)
    const int f = tid;                 // 0..575
    const int c = f / 9;
    const int r9 = f - c * 9;
    const int dy = r9 / 3 - 1;
    const int dx = r9 - (r9 / 3) * 3 - 1;
    const float* xp = x + (size_t)(b * NC + c) * (NH * NW);
    float s = 0.f;
    #pragma unroll 4
    for (int i = 0; i < cnt; ++i) {
        int n = list[i];
        int y  = (n >> 6) + dy;
        int xx = (n & 63) + dx;
        if (((unsigned)y < 64u) & ((unsigned)xx < 64u))
            s += xp[(y << 6) + xx];
    }
    centers[bk * NF + f] = s / ((float)cnt + 1e-6f);
}

// ---------------------------------------------------------------------------
// Kernel 2: MLPs on centers (fp32) -> lowrank[8], bias[64]; expand per-cluster
// kernel W[f][o] = sum_r lowrank_r * base[r][f][o]; store TRANSPOSED bf16
// wt[bk][o][f] so MFMA B-fragments are 16B-contiguous along f.
// ---------------------------------------------------------------------------
extern "C" __global__ __launch_bounds__(256)
void k_expand(const float* __restrict__ centers,
              const float* __restrict__ lw1, const float* __restrict__ lb1,
              const float* __restrict__ lw2, const float* __restrict__ lb2,
              const float* __restrict__ lw3, const float* __restrict__ lb3,
              const float* __restrict__ basek,
              const float* __restrict__ bw1, const float* __restrict__ bb1,
              const float* __restrict__ bw2, const float* __restrict__ bb2,
              unsigned short* __restrict__ wt, float* __restrict__ biasrows)
{
    const int bk = blockIdx.x;
    const int tid = threadIdx.x;
    __shared__ float c[NF];
    __shared__ float p1[8][NMLP], pb[8][NMLP];
    __shared__ float h1[NMLP], h2[NMLP], hb[NMLP], lr8[NRANK];

    for (int i = tid; i < NF; i += 256) c[i] = centers[bk * NF + i];
    __syncthreads();

    {   // layer-1 of both MLPs, parallel over (out_j, f-chunk)
        const int j = tid & 31, ch = tid >> 5;       // 8 chunks x 72 feats
        float a1 = 0.f, a2 = 0.f;
        for (int i = 0; i < 72; ++i) {
            int f = ch * 72 + i;
            float cv = c[f];
            a1 += cv * lw1[f * NMLP + j];
            a2 += cv * bw1[f * NMLP + j];
        }
        p1[ch][j] = a1; pb[ch][j] = a2;
    }
    __syncthreads();
    if (tid < NMLP) {
        float a = lb1[tid];
        for (int i = 0; i < 8; ++i) a += p1[i][tid];
        h1[tid] = fmaxf(a, 0.f);
    } else if (tid < 2 * NMLP) {
        int j = tid - NMLP;
        float a = bb1[j];
        for (int i = 0; i < 8; ++i) a += pb[i][j];
        hb[j] = fmaxf(a, 0.f);
    }
    __syncthreads();
    if (tid < NMLP) {
        float a = lb2[tid];
        for (int i = 0; i < NMLP; ++i) a += h1[i] * lw2[i * NMLP + tid];
        h2[tid] = fmaxf(a, 0.f);
    } else if (tid >= 64 && tid < 128) {
        int o = tid - 64;
        float a = bb2[o];
        for (int i = 0; i < NMLP; ++i) a += hb[i] * bw2[i * NOUT + o];
        biasrows[bk * NOUT + o] = a;
    }
    __syncthreads();
    if (tid < NRANK) {
        float a = lb3[tid];
        for (int i = 0; i < NMLP; ++i) a += h2[i] * lw3[i * NRANK + tid];
        lr8[tid] = a;
    }
    __syncthreads();

    const float l0 = lr8[0], l1 = lr8[1], l2 = lr8[2], l3 = lr8[3],
                l4 = lr8[4], l5 = lr8[5], l6 = lr8[6], l7 = lr8[7];
    unsigned short* dst = wt + (size_t)bk * (NF * NOUT);
    const int FO = NF * NOUT;
    for (int j = tid; j < FO; j += 256) {          // j = f*64 + o (coalesced reads)
        float a = l0 * basek[j]        + l1 * basek[FO + j]
                + l2 * basek[2*FO + j] + l3 * basek[3*FO + j]
                + l4 * basek[4*FO + j] + l5 * basek[5*FO + j]
                + l6 * basek[6*FO + j] + l7 * basek[7*FO + j];
        int f = j >> 6, o = j & 63;
        dst[o * NF + f] = f2bf(a);                 // transposed store; L2 merges
    }
}

// ---------------------------------------------------------------------------
// Kernel 3: gathered GEMM. 512 blocks = 2 per (b,k) (tile-strided), 256 thr.
// Per wave: 16 output cols, B-fragments register-resident (18 x short8).
// Per 32-pixel tile: stage A (patches bf16) in LDS (rows padded to 584),
// 18 x 2 mfma_f32_16x16x32_bf16, scatter-store with bias.
// blk%8 == b%8 -> per-batch L2 write combining on the scattered out stores.
// ---------------------------------------------------------------------------
extern "C" __global__ __launch_bounds__(256)
void k_main(const float* __restrict__ x, const unsigned short* __restrict__ lists,
            const int* __restrict__ counts, const unsigned short* __restrict__ wt,
            const float* __restrict__ biasrows, float* __restrict__ out)
{
    const int blk = blockIdx.x;
    const int b = blk & 15;
    const int jj = blk >> 4;            // 0..31
    const int k = jj >> 1, half = jj & 1;
    const int bk = k * 16 + b;
    const int tid = threadIdx.x;
    const int lane = tid & 63, wv = tid >> 6;
    const int quad = lane >> 4;
    const int l16 = lane & 15;
    const int cnt = counts[bk];

    __shared__ unsigned short list[NPIX];                 // 8 KB
    __shared__ __align__(16) unsigned short albuf[32 * 584]; // 36.5 KB, +8 pad/row
    __shared__ float biasl[NOUT];

    for (int i = tid; i < cnt; i += 256) list[i] = lists[bk * NPIX + i];
    if (tid < NOUT) biasl[tid] = biasrows[bk * NOUT + tid];

    // B fragments: wave wv owns cols o = wv*16 + l16; k-slices quad*8..+7
    const int col = wv * 16 + l16;
    s16x8 bfr[18];
    const unsigned short* wrow = wt + (size_t)bk * (NF * NOUT) + col * NF + quad * 8;
    #pragma unroll
    for (int ks = 0; ks < 18; ++ks)
        bfr[ks] = *reinterpret_cast<const s16x8*>(wrow + ks * 32);
    __syncthreads();

    const int ntile = (cnt + 31) >> 5;
    for (int t = half; t < ntile; t += 2) {
        // stage A: unit e = (pixel p, channel cch, row-offset dy) -> 3 taps
        for (int e = tid; e < 32 * 64 * 3; e += 256) {
            int p = e / 192;
            int rem = e - p * 192;
            int cch = rem / 3;
            int dy = rem - cch * 3;
            int slot = (t << 5) + p;
            unsigned short v0 = 0, v1 = 0, v2 = 0;
            if (slot < cnt) {
                int n = list[slot];
                int y = (n >> 6) + dy - 1;
                if ((unsigned)y < 64u) {
                    int xx = n & 63;
                    const float* row = x + ((size_t)(b * NC + cch) * NH + y) * NW;
                    if (xx > 0)  v0 = f2bf(row[xx - 1]);
                    v1 = f2bf(row[xx]);
                    if (xx < 63) v2 = f2bf(row[xx + 1]);
                }
            }
            int off = p * 584 + cch * 9 + dy * 3;
            albuf[off] = v0; albuf[off + 1] = v1; albuf[off + 2] = v2;
        }
        __syncthreads();

        f32x4 acc0 = {0.f, 0.f, 0.f, 0.f}, acc1 = {0.f, 0.f, 0.f, 0.f};
        const unsigned short* ar0 = albuf + l16 * 584 + quad * 8;
        const unsigned short* ar1 = ar0 + 16 * 584;
        #pragma unroll
        for (int ks = 0; ks < 18; ++ks) {
            s16x8 a0 = *reinterpret_cast<const s16x8*>(ar0 + ks * 32);
            s16x8 a1 = *reinterpret_cast<const s16x8*>(ar1 + ks * 32);
            acc0 = __builtin_amdgcn_mfma_f32_16x16x32_bf16(a0, bfr[ks], acc0, 0, 0, 0);
            acc1 = __builtin_amdgcn_mfma_f32_16x16x32_bf16(a1, bfr[ks], acc1, 0, 0, 0);
        }
        __syncthreads();

        // D layout: col = lane&15 (-> o), row = quad*4 + reg (-> pixel slot)
        float bb = biasl[col];
        float* ob = out + (size_t)(b * NOUT + col) * NPIX;
        #pragma unroll
        for (int r = 0; r < 4; ++r) {
            int m0 = (t << 5) + quad * 4 + r;
            if (m0 < cnt) ob[list[m0]] = acc0[r] + bb;
            int m1 = m0 + 16;
            if (m1 < cnt) ob[list[m1]] = acc1[r] + bb;
        }
    }
}

// ---------------------------------------------------------------------------
// Workspace layout (needs ~20.6 MB of d_ws):
//   lists    @ 0        : 256 * 4096 u16  = 2 MB
//   counts   @ 2097152  : 256 i32
//   centers  @ 2098176  : 256 * 576 f32   = 576 KB
//   biasrows @ 2688000  : 256 * 64 f32    = 64 KB
//   wt       @ 2753536  : 256 * 64 * 576 bf16 = 18.9 MB  (o-major, f-contig)
// ---------------------------------------------------------------------------
extern "C" void kernel_launch(void* const* d_in, const int* in_sizes, int n_in,
                              void* d_out, int out_size, void* d_ws, size_t ws_size,
                              hipStream_t stream)
{
    const float* x      = (const float*)d_in[0];
    const int*   labels = (const int*)d_in[1];
    const float* lw1    = (const float*)d_in[2];
    const float* lb1    = (const float*)d_in[3];
    const float* lw2    = (const float*)d_in[4];
    const float* lb2    = (const float*)d_in[5];
    const float* lw3    = (const float*)d_in[6];
    const float* lb3    = (const float*)d_in[7];
    const float* basek  = (const float*)d_in[8];
    const float* bw1    = (const float*)d_in[9];
    const float* bb1    = (const float*)d_in[10];
    const float* bw2    = (const float*)d_in[11];
    const float* bb2    = (const float*)d_in[12];
    float* out = (float*)d_out;

    char* ws = (char*)d_ws;
    unsigned short* lists   = (unsigned short*)ws;
    int*            counts  = (int*)(ws + 2097152);
    float*          centers = (float*)(ws + 2098176);
    float*          biasrows= (float*)(ws + 2688000);
    unsigned short* wt      = (unsigned short*)(ws + 2753536);

    k_centers<<<256, 576, 0, stream>>>(x, labels, lists, counts, centers);
    k_expand<<<256, 256, 0, stream>>>(centers, lw1, lb1, lw2, lb2, lw3, lb3,
                                      basek, bw1, bb1, bw2, bb2, wt, biasrows);
    k_main<<<512, 256, 0, stream>>>(x, lists, counts, wt, biasrows, out);
}

// Round 3
// 180.895 us; speedup vs baseline: 1.7552x; 1.7552x over previous
//
#include <hip/hip_runtime.h>
#include <stdint.h>
#include <stddef.h>

// Problem constants
#define NB   16
#define NC   64
#define NH   64
#define NW   64
#define KC   16
#define NOUT 64
#define NRANK 8
#define NMLP 32
#define NF   576      // C*3*3
#define NPIX 4096     // H*W
#define XH   66       // halo height/width for channel-last copy

typedef short s16x8 __attribute__((ext_vector_type(8)));
typedef float f32x4 __attribute__((ext_vector_type(4)));

__device__ __forceinline__ unsigned short f2bf(float x) {
    union { float f; uint32_t u; } v; v.f = x;
    uint32_t r = v.u + 0x7FFFu + ((v.u >> 16) & 1u);   // RTNE
    return (unsigned short)(r >> 16);
}
__device__ __forceinline__ float bf2f(unsigned short u) {
    union { uint32_t u; float f; } v; v.u = ((uint32_t)u) << 16;
    return v.f;
}

// ---------------------------------------------------------------------------
// k_prep: x [B][C][H][W] f32 -> xcl [B][66][66][64] bf16 channel-last with a
// zero halo. Coalesced via LDS transpose. grid = 66*16 (yy*16 + b), 256 thr.
// ---------------------------------------------------------------------------
extern "C" __global__ __launch_bounds__(256)
void k_prep(const float* __restrict__ x, unsigned short* __restrict__ xcl)
{
    const int blk = blockIdx.x;
    const int b = blk & 15, yy = blk >> 4;
    const int tid = threadIdx.x;
    unsigned short* dst = xcl + ((size_t)(b * XH + yy) * XH) * 64;
    if (yy == 0 || yy == XH - 1) {
        for (int e = tid; e < XH * 64; e += 256) dst[e] = 0;
        return;
    }
    __shared__ float tile[64 * 65];
    const int y = yy - 1;
    const float* src = x + (size_t)b * NC * (NH * NW) + y * NW;
    #pragma unroll
    for (int rr = 0; rr < 16; ++rr) {
        int c = rr * 4 + (tid >> 6);
        int xx = tid & 63;
        tile[c * 65 + xx] = src[(size_t)c * (NH * NW) + xx];
    }
    __syncthreads();
    for (int e = tid; e < XH * 64; e += 256) {
        int xx = e >> 6, c = e & 63;
        float v = (xx == 0 || xx == XH - 1) ? 0.f : tile[c * 65 + (xx - 1)];
        dst[e] = f2bf(v);
    }
}

// ---------------------------------------------------------------------------
// k_prepT: basek [R][F][O] (F = c*9+tap) -> basekT bf16 [R][O][f'] with
// f' = tap*64 + c. grid = 72 (r*9 + tap), 256 thr.
// ---------------------------------------------------------------------------
extern "C" __global__ __launch_bounds__(256)
void k_prepT(const float* __restrict__ basek, unsigned short* __restrict__ basekT)
{
    const int blk = blockIdx.x;
    const int r = blk / 9, tap = blk - r * 9;
    const int tid = threadIdx.x;
    __shared__ float tile[64 * 65];
    #pragma unroll
    for (int rr = 0; rr < 16; ++rr) {
        int c = rr * 4 + (tid >> 6);
        int o = tid & 63;
        tile[c * 65 + o] = basek[((size_t)r * NF + c * 9 + tap) * NOUT + o];
    }
    __syncthreads();
    #pragma unroll
    for (int rr = 0; rr < 16; ++rr) {
        int o = rr * 4 + (tid >> 6);
        int c = tid & 63;
        basekT[((size_t)r * NOUT + o) * NF + tap * 64 + c] = f2bf(tile[c * 65 + o]);
    }
}

// ---------------------------------------------------------------------------
// k_centers: per-(b,k) order-preserving pixel list + slot map + counts +
// cluster centers (coalesced gathers from L2-resident xcl: wave=tap, lane=c).
// grid 256 (k*16+b), 576 thr.
// ---------------------------------------------------------------------------
extern "C" __global__ __launch_bounds__(576)
void k_centers(const unsigned short* __restrict__ xcl, const int* __restrict__ labels,
               unsigned short* __restrict__ lists, unsigned short* __restrict__ slotmap,
               int* __restrict__ counts, float* __restrict__ centers)
{
    const int bk = blockIdx.x;
    const int b = bk & 15, k = bk >> 4;
    __shared__ unsigned short list[NPIX];   // 8 KB
    __shared__ int wcnt[9];
    const int tid = threadIdx.x;
    const int lane = tid & 63, wv = tid >> 6;
    const int* lab = labels + b * NPIX;

    int total = 0;
    for (int base = 0; base < NPIX; base += 576) {
        int n = base + tid;
        bool pred = (n < NPIX) && (lab[n] == k);
        unsigned long long m = __ballot(pred);
        if (lane == 0) wcnt[wv] = __popcll(m);
        int pre = __popcll(m & ((1ull << lane) - 1ull));
        __syncthreads();
        int wbase = total;
        for (int i = 0; i < wv; ++i) wbase += wcnt[i];
        int nt = total;
        for (int i = 0; i < 9; ++i) nt += wcnt[i];
        if (pred) {
            int slot = wbase + pre;
            list[slot] = (unsigned short)n;
            slotmap[b * NPIX + n] = (unsigned short)slot;
        }
        total = nt;
        __syncthreads();
    }
    const int cnt = total;
    unsigned short* gl = lists + bk * NPIX;
    for (int i = tid; i < cnt; i += 576) gl[i] = list[i];
    if (tid == 0) counts[bk] = cnt;

    // segmented mean gather: wave wv = tap, lane = c
    const int tap = wv;
    const int c = lane;
    const int dy = tap / 3, dx = tap - dy * 3;       // halo offsets 0..2
    const unsigned short* xb = xcl + (size_t)b * (XH * XH * 64);
    float s0 = 0.f, s1 = 0.f;
    int i = 0;
    #pragma unroll 4
    for (; i + 1 < cnt; i += 2) {
        int n0 = list[i], n1 = list[i + 1];
        s0 += bf2f(xb[((((n0 >> 6) + dy) * XH) + (n0 & 63) + dx) * 64 + c]);
        s1 += bf2f(xb[((((n1 >> 6) + dy) * XH) + (n1 & 63) + dx) * 64 + c]);
    }
    if (i < cnt) {
        int n0 = list[i];
        s0 += bf2f(xb[((((n0 >> 6) + dy) * XH) + (n0 & 63) + dx) * 64 + c]);
    }
    centers[bk * NF + c * 9 + tap] = (s0 + s1) / ((float)cnt + 1e-6f);
}

// ---------------------------------------------------------------------------
// k_expand: MLPs on centers (fp32) -> lr[bk][8] and biasrows[bk][64] only.
// (Cluster kernel expansion moved into k_main.)
// ---------------------------------------------------------------------------
extern "C" __global__ __launch_bounds__(256)
void k_expand(const float* __restrict__ centers,
              const float* __restrict__ lw1, const float* __restrict__ lb1,
              const float* __restrict__ lw2, const float* __restrict__ lb2,
              const float* __restrict__ lw3, const float* __restrict__ lb3,
              const float* __restrict__ bw1, const float* __restrict__ bb1,
              const float* __restrict__ bw2, const float* __restrict__ bb2,
              float* __restrict__ lrout, float* __restrict__ biasrows)
{
    const int bk = blockIdx.x;
    const int tid = threadIdx.x;
    __shared__ float c[NF];
    __shared__ float p1[8][NMLP], pb[8][NMLP];
    __shared__ float h1[NMLP], h2[NMLP], hb[NMLP];

    for (int i = tid; i < NF; i += 256) c[i] = centers[bk * NF + i];
    __syncthreads();

    {   // layer-1 of both MLPs
        const int j = tid & 31, ch = tid >> 5;       // 8 chunks x 72 feats
        float a1 = 0.f, a2 = 0.f;
        for (int i = 0; i < 72; ++i) {
            int f = ch * 72 + i;
            float cv = c[f];
            a1 += cv * lw1[f * NMLP + j];
            a2 += cv * bw1[f * NMLP + j];
        }
        p1[ch][j] = a1; pb[ch][j] = a2;
    }
    __syncthreads();
    if (tid < NMLP) {
        float a = lb1[tid];
        for (int i = 0; i < 8; ++i) a += p1[i][tid];
        h1[tid] = fmaxf(a, 0.f);
    } else if (tid < 2 * NMLP) {
        int j = tid - NMLP;
        float a = bb1[j];
        for (int i = 0; i < 8; ++i) a += pb[i][j];
        hb[j] = fmaxf(a, 0.f);
    }
    __syncthreads();
    if (tid < NMLP) {
        float a = lb2[tid];
        for (int i = 0; i < NMLP; ++i) a += h1[i] * lw2[i * NMLP + tid];
        h2[tid] = fmaxf(a, 0.f);
    } else if (tid >= 64 && tid < 128) {
        int o = tid - 64;
        float a = bb2[o];
        for (int i = 0; i < NMLP; ++i) a += hb[i] * bw2[i * NOUT + o];
        biasrows[bk * NOUT + o] = a;
    }
    __syncthreads();
    if (tid < NRANK) {
        float a = lb3[tid];
        for (int i = 0; i < NMLP; ++i) a += h2[i] * lw3[i * NRANK + tid];
        lrout[bk * NRANK + tid] = a;
    }
}

// ---------------------------------------------------------------------------
// k_main: gathered GEMM. grid 512 = 2 splits x 256 (b,k); 256 thr.
// B-fragments built on the fly per lane from bf16 basekT + lr (register-
// resident, 18 x s16x8). A staged per 32-pixel tile from xcl (9 x 16B loads +
// ds_write_b128, no bounds checks). Output compact bf16 outc[b][ptr][o].
// ---------------------------------------------------------------------------
extern "C" __global__ __launch_bounds__(256, 2)
void k_main(const unsigned short* __restrict__ xcl, const unsigned short* __restrict__ lists,
            const int* __restrict__ counts, const unsigned short* __restrict__ basekT,
            const float* __restrict__ lr, const float* __restrict__ biasrows,
            unsigned short* __restrict__ outc)
{
    const int blk = blockIdx.x;
    const int bk = blk & 255, split = blk >> 8;
    const int b = bk & 15, k = bk >> 4;
    const int tid = threadIdx.x;
    const int lane = tid & 63, wv = tid >> 6;
    const int quad = lane >> 4, l16 = lane & 15;
    const int cnt = counts[bk];

    int prefix = 0;
    for (int kk = 0; kk < k; ++kk) prefix += counts[kk * 16 + b];

    __shared__ unsigned short list[NPIX];                     // 8 KB
    __shared__ __align__(16) unsigned short albuf[32 * 584];  // 36.5 KB
    __shared__ float biasl[NOUT];

    for (int i = tid; i < cnt; i += 256) list[i] = lists[bk * NPIX + i];
    if (tid < NOUT) biasl[tid] = biasrows[bk * NOUT + tid];

    // Build B fragments: wave wv owns cols o = wv*16 + l16; k-slices quad*8..+7
    // bfr[ks][j] = sum_r lr[r] * basekT[r][col][quad*8 + ks*32 + j]
    const int col = wv * 16 + l16;
    float l8[NRANK];
    #pragma unroll
    for (int r = 0; r < NRANK; ++r) l8[r] = lr[bk * NRANK + r];
    const unsigned short* bbase = basekT + col * NF + quad * 8;
    s16x8 bfr[18];
    #pragma unroll
    for (int ks = 0; ks < 18; ++ks) {
        float w[8] = {0.f, 0.f, 0.f, 0.f, 0.f, 0.f, 0.f, 0.f};
        #pragma unroll
        for (int r = 0; r < NRANK; ++r) {
            s16x8 bv = *reinterpret_cast<const s16x8*>(bbase + r * (NOUT * NF) + ks * 32);
            #pragma unroll
            for (int j = 0; j < 8; ++j)
                w[j] += l8[r] * bf2f((unsigned short)bv[j]);
        }
        s16x8 f;
        #pragma unroll
        for (int j = 0; j < 8; ++j) f[j] = (short)f2bf(w[j]);
        bfr[ks] = f;
    }
    __syncthreads();

    const unsigned short* xb = xcl + (size_t)b * (XH * XH * 64);
    const int p = tid >> 3, part = tid & 7;      // staging role: pixel, 16B part
    const int ntile = (cnt + 31) >> 5;
    for (int t = split; t < ntile; t += 2) {
        int slot = (t << 5) + p;
        int n = (slot < cnt) ? list[slot] : 0;
        const unsigned short* xrow = xb + (((n >> 6) * XH) + (n & 63)) * 64;
        unsigned short* arow = albuf + p * 584 + part * 8;
        #pragma unroll
        for (int tap = 0; tap < 9; ++tap) {
            int dy = tap / 3, dx = tap - dy * 3;
            s16x8 v = *reinterpret_cast<const s16x8*>(xrow + (dy * XH + dx) * 64 + part * 8);
            *reinterpret_cast<s16x8*>(arow + tap * 64) = v;
        }
        __syncthreads();

        f32x4 acc0 = {0.f, 0.f, 0.f, 0.f}, acc1 = {0.f, 0.f, 0.f, 0.f};
        const unsigned short* ar0 = albuf + l16 * 584 + quad * 8;
        const unsigned short* ar1 = ar0 + 16 * 584;
        #pragma unroll
        for (int ks = 0; ks < 18; ++ks) {
            s16x8 a0 = *reinterpret_cast<const s16x8*>(ar0 + ks * 32);
            s16x8 a1 = *reinterpret_cast<const s16x8*>(ar1 + ks * 32);
            acc0 = __builtin_amdgcn_mfma_f32_16x16x32_bf16(a0, bfr[ks], acc0, 0, 0, 0);
            acc1 = __builtin_amdgcn_mfma_f32_16x16x32_bf16(a1, bfr[ks], acc1, 0, 0, 0);
        }
        __syncthreads();

        // D: col = l16 (-> o), row = quad*4 + reg (-> slot)
        float bb = biasl[col];
        unsigned short* ob = outc + ((size_t)b * NPIX + prefix) * 64;
        #pragma unroll
        for (int r = 0; r < 4; ++r) {
            int s0 = (t << 5) + quad * 4 + r;
            if (s0 < cnt) ob[(size_t)s0 * 64 + col] = f2bf(acc0[r] + bb);
            int s1 = s0 + 16;
            if (s1 < cnt) ob[(size_t)s1 * 64 + col] = f2bf(acc1[r] + bb);
        }
    }
}

// ---------------------------------------------------------------------------
// k_scatter: outc bf16 [b][ptr][o] -> out f32 [b][o][n] (coalesced stores).
// ptr = prefix[b][lab(n)] + slot(n). grid 512 = (ohalf*16 + chunk)*16 + b.
// ---------------------------------------------------------------------------
extern "C" __global__ __launch_bounds__(256)
void k_scatter(const int* __restrict__ labels, const unsigned short* __restrict__ slotmap,
               const int* __restrict__ counts, const unsigned short* __restrict__ outc,
               float* __restrict__ out)
{
    const int blk = blockIdx.x;
    const int b = blk & 15;
    const int chunk = (blk >> 4) & 15;
    const int ohalf = blk >> 8;
    const int tid = threadIdx.x;
    __shared__ int pref[KC];
    if (tid < KC) {
        int s = 0;
        for (int kk = 0; kk < tid; ++kk) s += counts[kk * 16 + b];
        pref[tid] = s;
    }
    __syncthreads();
    const int n = chunk * 256 + tid;
    const int kk = labels[b * NPIX + n];
    const int ptr = pref[kk] + slotmap[b * NPIX + n];
    const s16x8* src = (const s16x8*)(outc + ((size_t)b * NPIX + ptr) * 64 + ohalf * 32);
    s16x8 v[4];
    #pragma unroll
    for (int i = 0; i < 4; ++i) v[i] = src[i];
    float* ob = out + ((size_t)b * NOUT + ohalf * 32) * NPIX + n;
    #pragma unroll
    for (int i = 0; i < 4; ++i)
        #pragma unroll
        for (int j = 0; j < 8; ++j)
            ob[(size_t)(i * 8 + j) * NPIX] = bf2f((unsigned short)v[i][j]);
}

// ---------------------------------------------------------------------------
// Workspace layout — TOTAL 20,792,320 B (< 21,627,904 B proven safe in R1):
//   lists    @ 0         : 256*4096 u16      = 2,097,152
//   counts   @ 2097152   : 256 i32           = 1,024
//   centers  @ 2098176   : 256*576 f32       = 589,824
//   biasrows @ 2688000   : 256*64 f32        = 65,536
//   lr       @ 2753536   : 256*8 f32         = 8,192
//   basekT   @ 2761728   : 8*64*576 bf16     = 589,824
//   slotmap  @ 3351552   : 16*4096 u16       = 131,072
//   xcl      @ 3482624   : 16*66*66*64 bf16  = 8,921,088
//   outc     @ 12403712  : 16*4096*64 bf16   = 8,388,608
// ---------------------------------------------------------------------------
extern "C" void kernel_launch(void* const* d_in, const int* in_sizes, int n_in,
                              void* d_out, int out_size, void* d_ws, size_t ws_size,
                              hipStream_t stream)
{
    const float* x      = (const float*)d_in[0];
    const int*   labels = (const int*)d_in[1];
    const float* lw1    = (const float*)d_in[2];
    const float* lb1    = (const float*)d_in[3];
    const float* lw2    = (const float*)d_in[4];
    const float* lb2    = (const float*)d_in[5];
    const float* lw3    = (const float*)d_in[6];
    const float* lb3    = (const float*)d_in[7];
    const float* basek  = (const float*)d_in[8];
    const float* bw1    = (const float*)d_in[9];
    const float* bb1    = (const float*)d_in[10];
    const float* bw2    = (const float*)d_in[11];
    const float* bb2    = (const float*)d_in[12];
    float* out = (float*)d_out;

    char* ws = (char*)d_ws;
    unsigned short* lists   = (unsigned short*)(ws);
    int*            counts  = (int*)(ws + 2097152);
    float*          centers = (float*)(ws + 2098176);
    float*          biasrows= (float*)(ws + 2688000);
    float*          lr      = (float*)(ws + 2753536);
    unsigned short* basekT  = (unsigned short*)(ws + 2761728);
    unsigned short* slotmap = (unsigned short*)(ws + 3351552);
    unsigned short* xcl     = (unsigned short*)(ws + 3482624);
    unsigned short* outc    = (unsigned short*)(ws + 12403712);

    k_prep<<<XH * 16, 256, 0, stream>>>(x, xcl);
    k_prepT<<<72, 256, 0, stream>>>(basek, basekT);
    k_centers<<<256, 576, 0, stream>>>(xcl, labels, lists, slotmap, counts, centers);
    k_expand<<<256, 256, 0, stream>>>(centers, lw1, lb1, lw2, lb2, lw3, lb3,
                                      bw1, bb1, bw2, bb2, lr, biasrows);
    k_main<<<512, 256, 0, stream>>>(xcl, lists, counts, basekT, lr, biasrows, outc);
    k_scatter<<<512, 256, 0, stream>>>(labels, slotmap, counts, outc, out);
}